// Round 1
// baseline (879.747 us; speedup 1.0000x reference)
//
#include <hip/hip_runtime.h>
#include <stdint.h>

#define S_LEN 4096
#define DMODEL 768
#define NHEAD 12
#define DHEAD 64
#define NBLK 64
#define FF 3072
#define NLAYER 2

typedef __attribute__((ext_vector_type(8))) short short8;
typedef __attribute__((ext_vector_type(4))) float floatx4;
typedef unsigned short ushort_t;

// ---------- helpers ----------
__device__ __forceinline__ unsigned short f2bf(float f) {
    union { float f; unsigned u; } v; v.f = f;
    unsigned r = v.u + 0x7FFFu + ((v.u >> 16) & 1u);  // RNE
    return (unsigned short)(r >> 16);
}

__device__ __forceinline__ void load_lds16(const void* g, void* l) {
    __builtin_amdgcn_global_load_lds((const __attribute__((address_space(1))) void*)g,
                                     (__attribute__((address_space(3))) void*)l, 16, 0, 0);
}

// ---------- embedding + LN ----------
__global__ void embed_ln_kernel(const int* __restrict__ ids, const float* __restrict__ wemb,
                                const float* __restrict__ pemb, const float* __restrict__ w,
                                const float* __restrict__ b, float* __restrict__ hf,
                                ushort_t* __restrict__ hb) {
    int s = blockIdx.x, t = threadIdx.x;
    const float* we = wemb + (size_t)ids[s] * DMODEL;
    const float* pe = pemb + (size_t)s * DMODEL;
    float x0 = we[t] + pe[t];
    float x1 = we[t + 256] + pe[t + 256];
    float x2 = we[t + 512] + pe[t + 512];
    float sum = x0 + x1 + x2;
    float sum2 = x0 * x0 + x1 * x1 + x2 * x2;
    __shared__ float sred[8];
    for (int o = 32; o >= 1; o >>= 1) { sum += __shfl_down(sum, o); sum2 += __shfl_down(sum2, o); }
    if ((t & 63) == 0) { sred[t >> 6] = sum; sred[4 + (t >> 6)] = sum2; }
    __syncthreads();
    float ts = sred[0] + sred[1] + sred[2] + sred[3];
    float ts2 = sred[4] + sred[5] + sred[6] + sred[7];
    float mu = ts * (1.0f / DMODEL);
    float rs = rsqrtf(ts2 * (1.0f / DMODEL) - mu * mu + 1e-12f);
    size_t base = (size_t)s * DMODEL;
    float y0 = (x0 - mu) * rs * w[t] + b[t];
    float y1 = (x1 - mu) * rs * w[t + 256] + b[t + 256];
    float y2 = (x2 - mu) * rs * w[t + 512] + b[t + 512];
    hf[base + t] = y0; hf[base + t + 256] = y1; hf[base + t + 512] = y2;
    hb[base + t] = f2bf(y0); hb[base + t + 256] = f2bf(y1); hb[base + t + 512] = f2bf(y2);
}

// ---------- LN over precomputed sum rows ----------
__global__ void ln_kernel(const float* __restrict__ in, const float* __restrict__ w,
                          const float* __restrict__ b, float* __restrict__ hf,
                          ushort_t* __restrict__ hb) {
    int s = blockIdx.x, t = threadIdx.x;
    const float* row = in + (size_t)s * DMODEL;
    float x0 = row[t], x1 = row[t + 256], x2 = row[t + 512];
    float sum = x0 + x1 + x2;
    float sum2 = x0 * x0 + x1 * x1 + x2 * x2;
    __shared__ float sred[8];
    for (int o = 32; o >= 1; o >>= 1) { sum += __shfl_down(sum, o); sum2 += __shfl_down(sum2, o); }
    if ((t & 63) == 0) { sred[t >> 6] = sum; sred[4 + (t >> 6)] = sum2; }
    __syncthreads();
    float ts = sred[0] + sred[1] + sred[2] + sred[3];
    float ts2 = sred[4] + sred[5] + sred[6] + sred[7];
    float mu = ts * (1.0f / DMODEL);
    float rs = rsqrtf(ts2 * (1.0f / DMODEL) - mu * mu + 1e-12f);
    size_t base = (size_t)s * DMODEL;
    float y0 = (x0 - mu) * rs * w[t] + b[t];
    float y1 = (x1 - mu) * rs * w[t + 256] + b[t + 256];
    float y2 = (x2 - mu) * rs * w[t + 512] + b[t + 512];
    hf[base + t] = y0; hf[base + t + 256] = y1; hf[base + t + 512] = y2;
    hb[base + t] = f2bf(y0); hb[base + t + 256] = f2bf(y1); hb[base + t + 512] = f2bf(y2);
}

// ---------- fp32 (K x N) -> bf16 transposed (N x K) ----------
__global__ void transpose_cvt(const float* __restrict__ src, ushort_t* __restrict__ dst,
                              int K, int N) {
    __shared__ float tile[32][33];
    int n0 = blockIdx.x * 32, k0 = blockIdx.y * 32;
    int tx = threadIdx.x, ty = threadIdx.y;  // 32 x 8
    for (int i = 0; i < 32; i += 8)
        tile[ty + i][tx] = src[(size_t)(k0 + ty + i) * N + n0 + tx];
    __syncthreads();
    for (int i = 0; i < 32; i += 8)
        dst[(size_t)(n0 + ty + i) * K + k0 + tx] = f2bf(tile[tx][ty + i]);
}

// ---------- bf16 MFMA GEMM: C(MxN) = A(MxK) @ BT(NxK)^T, fused epilogues ----------
// MODE 0: QKV scatter (bias, q*0.125, per-head layout)
// MODE 1: out_f32 = acc + bias[n] + resid[m,n]
// MODE 2: out_bf16 = gelu(acc + bias[n])
template <int MODE>
__global__ __launch_bounds__(256, 2) void gemm_bf16(
    const ushort_t* __restrict__ A, const ushort_t* __restrict__ BT,
    int M, int N, int K,
    const float* __restrict__ bias, const float* __restrict__ resid,
    float* __restrict__ outf, ushort_t* __restrict__ outb,
    ushort_t* __restrict__ qout, ushort_t* __restrict__ kout, ushort_t* __restrict__ vout,
    const float* __restrict__ bq, const float* __restrict__ bk, const float* __restrict__ bv) {
    __shared__ __align__(16) ushort_t Asm[128 * 32];
    __shared__ __align__(16) ushort_t Bsm[128 * 32];
    int tid = threadIdx.x;
    int lane = tid & 63, wave = tid >> 6;
    int quad = lane >> 4, l16 = lane & 15;
    int wm = wave >> 1, wn = wave & 1;
    long arow0 = (long)blockIdx.y * 128;
    long bcol0 = (long)blockIdx.x * 128;
    // staging: lane -> (row-in-16, slot); XOR swizzle the *source* chunk so the
    // fixed dest (base + lane*16) ends up conflict-reduced for ds_read_b128.
    int rr = lane >> 2;
    int gchunk = (lane & 3) ^ (rr & 3) ^ ((rr >> 2) & 3);
    const ushort_t* agp0 = A + (arow0 + rr) * (long)K + gchunk * 8;
    const ushort_t* bgp0 = BT + (bcol0 + rr) * (long)K + gchunk * 8;
    int sl = quad ^ (l16 & 3) ^ ((l16 >> 2) & 3);  // read-side slot
    floatx4 acc[4][4];
#pragma unroll
    for (int i = 0; i < 4; i++)
#pragma unroll
        for (int j = 0; j < 4; j++) acc[i][j] = (floatx4){0.f, 0.f, 0.f, 0.f};

    for (int k0 = 0; k0 < K; k0 += 32) {
        __syncthreads();
#pragma unroll
        for (int t2 = 0; t2 < 2; t2++) {
            int seg = wave * 2 + t2;
            load_lds16(agp0 + (long)seg * 16 * K + k0, Asm + seg * 512);
            load_lds16(bgp0 + (long)seg * 16 * K + k0, Bsm + seg * 512);
        }
        __syncthreads();
        short8 af[4], bfv[4];
#pragma unroll
        for (int i = 0; i < 4; i++)
            af[i] = *(const short8*)&Asm[(wm * 64 + i * 16 + l16) * 32 + sl * 8];
#pragma unroll
        for (int j = 0; j < 4; j++)
            bfv[j] = *(const short8*)&Bsm[(wn * 64 + j * 16 + l16) * 32 + sl * 8];
#pragma unroll
        for (int i = 0; i < 4; i++)
#pragma unroll
            for (int j = 0; j < 4; j++)
                acc[i][j] = __builtin_amdgcn_mfma_f32_16x16x32_bf16(af[i], bfv[j], acc[i][j], 0, 0, 0);
    }

#pragma unroll
    for (int i = 0; i < 4; i++) {
        long row = arow0 + wm * 64 + i * 16 + quad * 4;
#pragma unroll
        for (int j = 0; j < 4; j++) {
            long col = bcol0 + wn * 64 + j * 16 + l16;
#pragma unroll
            for (int r = 0; r < 4; r++) {
                float v = acc[i][j][r];
                long rw = row + r;
                if (MODE == 0) {
                    int n = (int)col;
                    if (n < DMODEL) {
                        v = (v + bq[n]) * 0.125f;  // 1/sqrt(64) folded into Q
                        int hh = n >> 6, dh = n & 63;
                        qout[((long)hh * S_LEN + rw) * DHEAD + dh] = f2bf(v);
                    } else if (n < 2 * DMODEL) {
                        int n2 = n - DMODEL; v += bk[n2];
                        int hh = n2 >> 6, dh = n2 & 63;
                        kout[((long)hh * S_LEN + rw) * DHEAD + dh] = f2bf(v);
                    } else {
                        int n2 = n - 2 * DMODEL; v += bv[n2];
                        int hh = n2 >> 6, dh = n2 & 63;
                        vout[((long)hh * S_LEN + rw) * DHEAD + dh] = f2bf(v);
                    }
                } else if (MODE == 1) {
                    v += bias[col] + resid[rw * (long)N + col];
                    outf[rw * (long)N + col] = v;
                } else {  // MODE 2: gelu(tanh approx) -> bf16
                    v += bias[col];
                    float u = 0.7978845608f * (v + 0.044715f * v * v * v);
                    v = 0.5f * v * (1.0f + tanhf(u));
                    outb[rw * (long)N + col] = f2bf(v);
                }
            }
        }
    }
}

// ---------- BigBird attention: one workgroup per (head, q-block), online softmax ----------
__global__ __launch_bounds__(256, 2) void attn_kernel(
    const ushort_t* __restrict__ qb, const ushort_t* __restrict__ kb,
    const ushort_t* __restrict__ vb, const int* __restrict__ randl,
    ushort_t* __restrict__ out) {
    __shared__ __align__(16) ushort_t Ks[64 * 72];   // [key][dh], padded
    __shared__ __align__(16) ushort_t Vs[64 * 72];   // [dh][key], padded
    __shared__ __align__(16) ushort_t Ps[4][16 * 72];  // per-wave P round-trip
    __shared__ int kls[8];
    int tid = threadIdx.x, lane = tid & 63, wave = tid >> 6, quad = lane >> 4, l16 = lane & 15;
    int g = blockIdx.x;
    int h, qblk, nkb;
    if (g < NHEAD) { h = g; qblk = 0; nkb = NBLK; }
    else if (g < 2 * NHEAD) { h = g - NHEAD; qblk = NBLK - 1; nkb = NBLK; }
    else {
        int m = g - 2 * NHEAD;
        h = m / (NBLK - 2);
        qblk = 1 + m % (NBLK - 2);
        nkb = 8;
    }
    bool edge = (nkb == NBLK);
    if (!edge && tid < 8) {
        int v;
        if (tid == 0) v = 0;
        else if (tid == 1) v = NBLK - 1;
        else if (tid == 2) v = qblk - 1;
        else if (tid == 3) v = qblk;
        else if (tid == 4) v = qblk + 1;
        else v = randl[(h * NBLK + qblk) * 3 + (tid - 5)];
        kls[tid] = v;
    }
    const ushort_t* qh = qb + (size_t)h * S_LEN * DHEAD;
    const ushort_t* kh = kb + (size_t)h * S_LEN * DHEAD;
    const ushort_t* vh = vb + (size_t)h * S_LEN * DHEAD;
    size_t qoff = ((size_t)(qblk * 64 + wave * 16 + l16)) * DHEAD;
    short8 qf0 = *(const short8*)&qh[qoff + quad * 8];
    short8 qf1 = *(const short8*)&qh[qoff + 32 + quad * 8];
    floatx4 oacc[4];
#pragma unroll
    for (int j = 0; j < 4; j++) oacc[j] = (floatx4){0.f, 0.f, 0.f, 0.f};
    float mrun[4] = {-1e30f, -1e30f, -1e30f, -1e30f};
    float lrun[4] = {0.f, 0.f, 0.f, 0.f};

    for (int it = 0; it < nkb; ++it) {
        __syncthreads();  // staged LDS free to overwrite; also publishes kls on it==0
        int kbi = edge ? it : kls[it];
        {   // stage K block row-major (padded rows of 72)
            const ushort_t* src = kh + (size_t)kbi * 64 * DHEAD;
#pragma unroll
            for (int c = 0; c < 2; c++) {
                int chunk = tid + c * 256;  // 512 x 16B
                int krow = chunk >> 3, kc = chunk & 7;
                *(uint4*)&Ks[krow * 72 + kc * 8] = *(const uint4*)&src[chunk * 8];
            }
            // stage V transposed: wave handles dh rows [wave*16, wave*16+16)
            const ushort_t* vsrc = vh + (size_t)kbi * 64 * DHEAD;
#pragma unroll
            for (int c = 0; c < 2; c++) {
                int dh0 = wave * 16 + c * 8;
                uint4 d4 = *(const uint4*)&vsrc[lane * DHEAD + dh0];
                const ushort_t* e = (const ushort_t*)&d4;
#pragma unroll
                for (int j = 0; j < 8; j++) Vs[(dh0 + j) * 72 + lane] = e[j];
            }
        }
        __syncthreads();
        // S = Q @ K^T  (C layout: row=quad*4+r, col=jt*16+l16)
        floatx4 sacc[4];
#pragma unroll
        for (int jt = 0; jt < 4; jt++) {
            short8 kf0 = *(const short8*)&Ks[(jt * 16 + l16) * 72 + quad * 8];
            short8 kf1 = *(const short8*)&Ks[(jt * 16 + l16) * 72 + 32 + quad * 8];
            floatx4 z = (floatx4){0.f, 0.f, 0.f, 0.f};
            z = __builtin_amdgcn_mfma_f32_16x16x32_bf16(qf0, kf0, z, 0, 0, 0);
            z = __builtin_amdgcn_mfma_f32_16x16x32_bf16(qf1, kf1, z, 0, 0, 0);
            sacc[jt] = z;
        }
        // online softmax per q-row
#pragma unroll
        for (int r = 0; r < 4; r++) {
            float mx = fmaxf(fmaxf(sacc[0][r], sacc[1][r]), fmaxf(sacc[2][r], sacc[3][r]));
#pragma unroll
            for (int o = 1; o < 16; o <<= 1) mx = fmaxf(mx, __shfl_xor(mx, o));
            float mnew = fmaxf(mrun[r], mx);
            float al = __expf(mrun[r] - mnew);
            float pv[4], ps = 0.f;
#pragma unroll
            for (int jt = 0; jt < 4; jt++) { pv[jt] = __expf(sacc[jt][r] - mnew); ps += pv[jt]; }
#pragma unroll
            for (int o = 1; o < 16; o <<= 1) ps += __shfl_xor(ps, o);
            lrun[r] = lrun[r] * al + ps;
            mrun[r] = mnew;
#pragma unroll
            for (int jt = 0; jt < 4; jt++) {
                oacc[jt][r] *= al;
                Ps[wave][(quad * 4 + r) * 72 + jt * 16 + l16] = f2bf(pv[jt]);
            }
        }
        // O += P @ V  (P via LDS round-trip into A-operand layout)
        short8 pa0 = *(const short8*)&Ps[wave][l16 * 72 + quad * 8];
        short8 pa1 = *(const short8*)&Ps[wave][l16 * 72 + 32 + quad * 8];
#pragma unroll
        for (int jt = 0; jt < 4; jt++) {
            short8 vf0 = *(const short8*)&Vs[(jt * 16 + l16) * 72 + quad * 8];
            short8 vf1 = *(const short8*)&Vs[(jt * 16 + l16) * 72 + 32 + quad * 8];
            oacc[jt] = __builtin_amdgcn_mfma_f32_16x16x32_bf16(pa0, vf0, oacc[jt], 0, 0, 0);
            oacc[jt] = __builtin_amdgcn_mfma_f32_16x16x32_bf16(pa1, vf1, oacc[jt], 0, 0, 0);
        }
    }
#pragma unroll
    for (int jt = 0; jt < 4; jt++)
#pragma unroll
        for (int r = 0; r < 4; r++) {
            int row = qblk * 64 + wave * 16 + quad * 4 + r;
            int col = h * DHEAD + jt * 16 + l16;
            out[(size_t)row * DMODEL + col] = f2bf(oacc[jt][r] / lrun[r]);
        }
}

// ---------- classifier: out = h[S-1] @ Wc + bc ----------
__global__ void classifier_kernel(const float* __restrict__ hf, const float* __restrict__ Wc,
                                  const float* __restrict__ bc, float* __restrict__ out) {
    int t = threadIdx.x;
    int c = t & 7, seg = t >> 3;
    const float* hr = hf + (size_t)(S_LEN - 1) * DMODEL;
    float p = 0.f;
    for (int i = 0; i < 24; i++) { int d = seg * 24 + i; p += hr[d] * Wc[d * 8 + c]; }
    __shared__ float red[256];
    red[t] = p;
    __syncthreads();
    for (int o = 128; o >= 8; o >>= 1) { if (t < o) red[t] += red[t + o]; __syncthreads(); }
    if (t < 8) out[t] = red[t] + bc[t];
}

// ---------- launch ----------
extern "C" void kernel_launch(void* const* d_in, const int* in_sizes, int n_in,
                              void* d_out, int out_size, void* d_ws, size_t ws_size,
                              hipStream_t stream) {
    (void)in_sizes; (void)n_in; (void)out_size; (void)ws_size;
    const int* input_ids = (const int*)d_in[0];
    const int* rand_attn = (const int*)d_in[1];
    const float* word_emb = (const float*)d_in[2];
    const float* pos_emb = (const float*)d_in[3];
    const float* emb_ln_w = (const float*)d_in[4];
    const float* emb_ln_b = (const float*)d_in[5];
    const float* Wq = (const float*)d_in[6];
    const float* bq = (const float*)d_in[7];
    const float* Wk = (const float*)d_in[8];
    const float* bk = (const float*)d_in[9];
    const float* Wv = (const float*)d_in[10];
    const float* bv = (const float*)d_in[11];
    const float* Wo = (const float*)d_in[12];
    const float* bo = (const float*)d_in[13];
    const float* ln1_w = (const float*)d_in[14];
    const float* ln1_b = (const float*)d_in[15];
    const float* W1 = (const float*)d_in[16];
    const float* b1 = (const float*)d_in[17];
    const float* W2 = (const float*)d_in[18];
    const float* b2 = (const float*)d_in[19];
    const float* ln2_w = (const float*)d_in[20];
    const float* ln2_b = (const float*)d_in[21];
    const float* Wc = (const float*)d_in[22];
    const float* bc = (const float*)d_in[23];
    float* outp = (float*)d_out;

    char* ws = (char*)d_ws;
    size_t off = 0;
    auto alloc = [&](size_t bytes) -> void* {
        void* p = ws + off;
        off += (bytes + 255) & ~(size_t)255;
        return p;
    };
    float* hf = (float*)alloc((size_t)S_LEN * DMODEL * 4);
    ushort_t* hb = (ushort_t*)alloc((size_t)S_LEN * DMODEL * 2);
    float* res = (float*)alloc((size_t)S_LEN * DMODEL * 4);
    ushort_t* WqkvT = (ushort_t*)alloc((size_t)3 * DMODEL * DMODEL * 2);
    ushort_t* WoT = (ushort_t*)alloc((size_t)DMODEL * DMODEL * 2);
    ushort_t* W1T = (ushort_t*)alloc((size_t)FF * DMODEL * 2);
    ushort_t* W2T = (ushort_t*)alloc((size_t)DMODEL * FF * 2);
    ushort_t* qbuf = (ushort_t*)alloc((size_t)NHEAD * S_LEN * DHEAD * 2);
    ushort_t* kbuf = (ushort_t*)alloc((size_t)NHEAD * S_LEN * DHEAD * 2);
    ushort_t* vbuf = (ushort_t*)alloc((size_t)NHEAD * S_LEN * DHEAD * 2);
    ushort_t* attnb = (ushort_t*)alloc((size_t)S_LEN * DMODEL * 2);
    ushort_t* gbuf = (ushort_t*)alloc((size_t)S_LEN * FF * 2);

    dim3 blk256(256);
    dim3 tb(32, 8);

    embed_ln_kernel<<<S_LEN, blk256, 0, stream>>>(input_ids, word_emb, pos_emb,
                                                  emb_ln_w, emb_ln_b, hf, hb);

    for (int l = 0; l < NLAYER; ++l) {
        const float* Wq_l = Wq + (size_t)l * DMODEL * DMODEL;
        const float* Wk_l = Wk + (size_t)l * DMODEL * DMODEL;
        const float* Wv_l = Wv + (size_t)l * DMODEL * DMODEL;
        const float* Wo_l = Wo + (size_t)l * DMODEL * DMODEL;
        const float* W1_l = W1 + (size_t)l * DMODEL * FF;
        const float* W2_l = W2 + (size_t)l * FF * DMODEL;
        const float* bq_l = bq + (size_t)l * DMODEL;
        const float* bk_l = bk + (size_t)l * DMODEL;
        const float* bv_l = bv + (size_t)l * DMODEL;
        const float* bo_l = bo + (size_t)l * DMODEL;
        const float* b1_l = b1 + (size_t)l * FF;
        const float* b2_l = b2 + (size_t)l * DMODEL;
        const float* ln1w_l = ln1_w + (size_t)l * DMODEL;
        const float* ln1b_l = ln1_b + (size_t)l * DMODEL;
        const float* ln2w_l = ln2_w + (size_t)l * DMODEL;
        const float* ln2b_l = ln2_b + (size_t)l * DMODEL;
        const int* rand_l = rand_attn + (size_t)l * NHEAD * NBLK * 3;

        transpose_cvt<<<dim3(DMODEL / 32, DMODEL / 32), tb, 0, stream>>>(Wq_l, WqkvT, DMODEL, DMODEL);
        transpose_cvt<<<dim3(DMODEL / 32, DMODEL / 32), tb, 0, stream>>>(Wk_l, WqkvT + (size_t)DMODEL * DMODEL, DMODEL, DMODEL);
        transpose_cvt<<<dim3(DMODEL / 32, DMODEL / 32), tb, 0, stream>>>(Wv_l, WqkvT + (size_t)2 * DMODEL * DMODEL, DMODEL, DMODEL);
        transpose_cvt<<<dim3(DMODEL / 32, DMODEL / 32), tb, 0, stream>>>(Wo_l, WoT, DMODEL, DMODEL);
        transpose_cvt<<<dim3(FF / 32, DMODEL / 32), tb, 0, stream>>>(W1_l, W1T, DMODEL, FF);
        transpose_cvt<<<dim3(DMODEL / 32, FF / 32), tb, 0, stream>>>(W2_l, W2T, FF, DMODEL);

        gemm_bf16<0><<<dim3(3 * DMODEL / 128, S_LEN / 128), blk256, 0, stream>>>(
            hb, WqkvT, S_LEN, 3 * DMODEL, DMODEL,
            nullptr, nullptr, nullptr, nullptr, qbuf, kbuf, vbuf, bq_l, bk_l, bv_l);

        attn_kernel<<<NHEAD * NBLK, blk256, 0, stream>>>(qbuf, kbuf, vbuf, rand_l, attnb);

        gemm_bf16<1><<<dim3(DMODEL / 128, S_LEN / 128), blk256, 0, stream>>>(
            attnb, WoT, S_LEN, DMODEL, DMODEL,
            bo_l, hf, res, nullptr, nullptr, nullptr, nullptr, nullptr, nullptr, nullptr);

        ln_kernel<<<S_LEN, blk256, 0, stream>>>(res, ln1w_l, ln1b_l, hf, hb);

        gemm_bf16<2><<<dim3(FF / 128, S_LEN / 128), blk256, 0, stream>>>(
            hb, W1T, S_LEN, FF, DMODEL,
            b1_l, nullptr, nullptr, gbuf, nullptr, nullptr, nullptr, nullptr, nullptr, nullptr);

        gemm_bf16<1><<<dim3(DMODEL / 128, S_LEN / 128), blk256, 0, stream>>>(
            gbuf, W2T, S_LEN, DMODEL, FF,
            b2_l, hf, res, nullptr, nullptr, nullptr, nullptr, nullptr, nullptr, nullptr);

        ln_kernel<<<S_LEN, blk256, 0, stream>>>(res, ln2w_l, ln2b_l, hf, hb);
    }

    classifier_kernel<<<1, blk256, 0, stream>>>(hf, Wc, bc, outp);
}

// Round 2
// 737.261 us; speedup vs baseline: 1.1933x; 1.1933x over previous
//
#include <hip/hip_runtime.h>
#include <stdint.h>

#define S_LEN 4096
#define DMODEL 768
#define NHEAD 12
#define DHEAD 64
#define NBLK 64
#define FF 3072
#define NLAYER 2
#define NMID (NHEAD * (NBLK - 2))   // 744 mid workgroups
#define NEDGE_WG (NHEAD * 2 * 8)    // 192 edge partial workgroups

typedef __attribute__((ext_vector_type(8))) short short8;
typedef __attribute__((ext_vector_type(4))) float floatx4;
typedef unsigned short ushort_t;

// ---------- helpers ----------
__device__ __forceinline__ unsigned short f2bf(float f) {
    union { float f; unsigned u; } v; v.f = f;
    unsigned r = v.u + 0x7FFFu + ((v.u >> 16) & 1u);  // RNE
    return (unsigned short)(r >> 16);
}

__device__ __forceinline__ void load_lds16(const void* g, void* l) {
    __builtin_amdgcn_global_load_lds((const __attribute__((address_space(1))) void*)g,
                                     (__attribute__((address_space(3))) void*)l, 16, 0, 0);
}

// ---------- embedding + LN ----------
__global__ void embed_ln_kernel(const int* __restrict__ ids, const float* __restrict__ wemb,
                                const float* __restrict__ pemb, const float* __restrict__ w,
                                const float* __restrict__ b, float* __restrict__ hf,
                                ushort_t* __restrict__ hb) {
    int s = blockIdx.x, t = threadIdx.x;
    const float* we = wemb + (size_t)ids[s] * DMODEL;
    const float* pe = pemb + (size_t)s * DMODEL;
    float x0 = we[t] + pe[t];
    float x1 = we[t + 256] + pe[t + 256];
    float x2 = we[t + 512] + pe[t + 512];
    float sum = x0 + x1 + x2;
    float sum2 = x0 * x0 + x1 * x1 + x2 * x2;
    __shared__ float sred[8];
    for (int o = 32; o >= 1; o >>= 1) { sum += __shfl_down(sum, o); sum2 += __shfl_down(sum2, o); }
    if ((t & 63) == 0) { sred[t >> 6] = sum; sred[4 + (t >> 6)] = sum2; }
    __syncthreads();
    float ts = sred[0] + sred[1] + sred[2] + sred[3];
    float ts2 = sred[4] + sred[5] + sred[6] + sred[7];
    float mu = ts * (1.0f / DMODEL);
    float rs = rsqrtf(ts2 * (1.0f / DMODEL) - mu * mu + 1e-12f);
    size_t base = (size_t)s * DMODEL;
    float y0 = (x0 - mu) * rs * w[t] + b[t];
    float y1 = (x1 - mu) * rs * w[t + 256] + b[t + 256];
    float y2 = (x2 - mu) * rs * w[t + 512] + b[t + 512];
    hf[base + t] = y0; hf[base + t + 256] = y1; hf[base + t + 512] = y2;
    hb[base + t] = f2bf(y0); hb[base + t + 256] = f2bf(y1); hb[base + t + 512] = f2bf(y2);
}

// ---------- LN ----------
__global__ void ln_kernel(const float* __restrict__ in, const float* __restrict__ w,
                          const float* __restrict__ b, float* __restrict__ hf,
                          ushort_t* __restrict__ hb) {
    int s = blockIdx.x, t = threadIdx.x;
    const float* row = in + (size_t)s * DMODEL;
    float x0 = row[t], x1 = row[t + 256], x2 = row[t + 512];
    float sum = x0 + x1 + x2;
    float sum2 = x0 * x0 + x1 * x1 + x2 * x2;
    __shared__ float sred[8];
    for (int o = 32; o >= 1; o >>= 1) { sum += __shfl_down(sum, o); sum2 += __shfl_down(sum2, o); }
    if ((t & 63) == 0) { sred[t >> 6] = sum; sred[4 + (t >> 6)] = sum2; }
    __syncthreads();
    float ts = sred[0] + sred[1] + sred[2] + sred[3];
    float ts2 = sred[4] + sred[5] + sred[6] + sred[7];
    float mu = ts * (1.0f / DMODEL);
    float rs = rsqrtf(ts2 * (1.0f / DMODEL) - mu * mu + 1e-12f);
    size_t base = (size_t)s * DMODEL;
    float y0 = (x0 - mu) * rs * w[t] + b[t];
    float y1 = (x1 - mu) * rs * w[t + 256] + b[t + 256];
    float y2 = (x2 - mu) * rs * w[t + 512] + b[t + 512];
    hf[base + t] = y0; hf[base + t + 256] = y1; hf[base + t + 512] = y2;
    hb[base + t] = f2bf(y0); hb[base + t + 256] = f2bf(y1); hb[base + t + 512] = f2bf(y2);
}

// ---------- fp32 (K x N) -> bf16 transposed (N x K) ----------
__global__ void transpose_cvt(const float* __restrict__ src, ushort_t* __restrict__ dst,
                              int K, int N) {
    __shared__ float tile[32][33];
    int n0 = blockIdx.x * 32, k0 = blockIdx.y * 32;
    int tx = threadIdx.x, ty = threadIdx.y;  // 32 x 8
    for (int i = 0; i < 32; i += 8)
        tile[ty + i][tx] = src[(size_t)(k0 + ty + i) * N + n0 + tx];
    __syncthreads();
    for (int i = 0; i < 32; i += 8)
        dst[(size_t)(n0 + ty + i) * K + k0 + tx] = f2bf(tile[tx][ty + i]);
}

// ---------- bf16 MFMA GEMM with fused epilogues ----------
template <int MODE>
__global__ __launch_bounds__(256, 2) void gemm_bf16(
    const ushort_t* __restrict__ A, const ushort_t* __restrict__ BT,
    int M, int N, int K,
    const float* __restrict__ bias, const float* __restrict__ resid,
    float* __restrict__ outf, ushort_t* __restrict__ outb,
    ushort_t* __restrict__ qout, ushort_t* __restrict__ kout, ushort_t* __restrict__ vout,
    const float* __restrict__ bq, const float* __restrict__ bk, const float* __restrict__ bv) {
    __shared__ __align__(16) ushort_t Asm[128 * 32];
    __shared__ __align__(16) ushort_t Bsm[128 * 32];
    int tid = threadIdx.x;
    int lane = tid & 63, wave = tid >> 6;
    int quad = lane >> 4, l16 = lane & 15;
    int wm = wave >> 1, wn = wave & 1;
    long arow0 = (long)blockIdx.y * 128;
    long bcol0 = (long)blockIdx.x * 128;
    int rr = lane >> 2;
    int gchunk = (lane & 3) ^ (rr & 3) ^ ((rr >> 2) & 3);
    const ushort_t* agp0 = A + (arow0 + rr) * (long)K + gchunk * 8;
    const ushort_t* bgp0 = BT + (bcol0 + rr) * (long)K + gchunk * 8;
    int sl = quad ^ (l16 & 3) ^ ((l16 >> 2) & 3);
    floatx4 acc[4][4];
#pragma unroll
    for (int i = 0; i < 4; i++)
#pragma unroll
        for (int j = 0; j < 4; j++) acc[i][j] = (floatx4){0.f, 0.f, 0.f, 0.f};

    for (int k0 = 0; k0 < K; k0 += 32) {
        __syncthreads();
#pragma unroll
        for (int t2 = 0; t2 < 2; t2++) {
            int seg = wave * 2 + t2;
            load_lds16(agp0 + (long)seg * 16 * K + k0, Asm + seg * 512);
            load_lds16(bgp0 + (long)seg * 16 * K + k0, Bsm + seg * 512);
        }
        __syncthreads();
        short8 af[4], bfv[4];
#pragma unroll
        for (int i = 0; i < 4; i++)
            af[i] = *(const short8*)&Asm[(wm * 64 + i * 16 + l16) * 32 + sl * 8];
#pragma unroll
        for (int j = 0; j < 4; j++)
            bfv[j] = *(const short8*)&Bsm[(wn * 64 + j * 16 + l16) * 32 + sl * 8];
#pragma unroll
        for (int i = 0; i < 4; i++)
#pragma unroll
            for (int j = 0; j < 4; j++)
                acc[i][j] = __builtin_amdgcn_mfma_f32_16x16x32_bf16(af[i], bfv[j], acc[i][j], 0, 0, 0);
    }

#pragma unroll
    for (int i = 0; i < 4; i++) {
        long row = arow0 + wm * 64 + i * 16 + quad * 4;
#pragma unroll
        for (int j = 0; j < 4; j++) {
            long col = bcol0 + wn * 64 + j * 16 + l16;
#pragma unroll
            for (int r = 0; r < 4; r++) {
                float v = acc[i][j][r];
                long rw = row + r;
                if (MODE == 0) {
                    int n = (int)col;
                    if (n < DMODEL) {
                        v = (v + bq[n]) * 0.125f;
                        int hh = n >> 6, dh = n & 63;
                        qout[((long)hh * S_LEN + rw) * DHEAD + dh] = f2bf(v);
                    } else if (n < 2 * DMODEL) {
                        int n2 = n - DMODEL; v += bk[n2];
                        int hh = n2 >> 6, dh = n2 & 63;
                        kout[((long)hh * S_LEN + rw) * DHEAD + dh] = f2bf(v);
                    } else {
                        int n2 = n - 2 * DMODEL; v += bv[n2];
                        int hh = n2 >> 6, dh = n2 & 63;
                        vout[((long)hh * S_LEN + rw) * DHEAD + dh] = f2bf(v);
                    }
                } else if (MODE == 1) {
                    v += bias[col] + resid[rw * (long)N + col];
                    outf[rw * (long)N + col] = v;
                } else {
                    v += bias[col];
                    float u = 0.7978845608f * (v + 0.044715f * v * v * v);
                    v = 0.5f * v * (1.0f + tanhf(u));
                    outb[rw * (long)N + col] = f2bf(v);
                }
            }
        }
    }
}

// ---------- BigBird attention, load-balanced ----------
// Grid: [0,NMID) mid (h,qblk) with 8-entry kl-list; [NMID,NMID+192) edge partials:
// each edge (h, qblk in {0,63}) split into 8 chunks of 8 k-blocks (split-K flash).
// Edge partials write un-normalized O (fp32) + per-row (m,l); combine kernel merges.
__global__ __launch_bounds__(256, 2) void attn_kernel(
    const ushort_t* __restrict__ qb, const ushort_t* __restrict__ kb,
    const ushort_t* __restrict__ vb, const int* __restrict__ randl,
    ushort_t* __restrict__ out, float* __restrict__ opart, float* __restrict__ mlpart) {
    __shared__ __align__(16) ushort_t Ks[64 * 72];
    __shared__ __align__(16) ushort_t Vs[64 * 72];
    __shared__ __align__(16) ushort_t Ps[4][16 * 72];
    __shared__ int kls[8];
    int tid = threadIdx.x, lane = tid & 63, wave = tid >> 6, quad = lane >> 4, l16 = lane & 15;
    int g = blockIdx.x;
    int h, qblk, chunk = 0, eidx = 0;
    bool mid;
    if (g < NMID) {
        mid = true;
        h = g / (NBLK - 2);
        qblk = 1 + g % (NBLK - 2);
    } else {
        mid = false;
        int t = g - NMID;
        int side = t / (NHEAD * 8);   // 0: qblk 0, 1: qblk 63
        int t2 = t % (NHEAD * 8);
        h = t2 >> 3;
        chunk = t2 & 7;
        qblk = side ? (NBLK - 1) : 0;
        eidx = side * NHEAD + h;
    }
    if (mid && tid < 8) {
        int v;
        if (tid == 0) v = 0;
        else if (tid == 1) v = NBLK - 1;
        else if (tid == 2) v = qblk - 1;
        else if (tid == 3) v = qblk;
        else if (tid == 4) v = qblk + 1;
        else v = randl[(h * NBLK + qblk) * 3 + (tid - 5)];
        kls[tid] = v;
    }
    const ushort_t* qh = qb + (size_t)h * S_LEN * DHEAD;
    const ushort_t* kh = kb + (size_t)h * S_LEN * DHEAD;
    const ushort_t* vh = vb + (size_t)h * S_LEN * DHEAD;
    size_t qoff = ((size_t)(qblk * 64 + wave * 16 + l16)) * DHEAD;
    short8 qf0 = *(const short8*)&qh[qoff + quad * 8];
    short8 qf1 = *(const short8*)&qh[qoff + 32 + quad * 8];
    floatx4 oacc[4];
#pragma unroll
    for (int j = 0; j < 4; j++) oacc[j] = (floatx4){0.f, 0.f, 0.f, 0.f};
    float mrun[4] = {-1e30f, -1e30f, -1e30f, -1e30f};
    float lrun[4] = {0.f, 0.f, 0.f, 0.f};

    for (int it = 0; it < 8; ++it) {
        __syncthreads();  // publishes kls on it==0; staged LDS free to overwrite
        int kbi = mid ? kls[it] : (chunk * 8 + it);
        {
            const ushort_t* src = kh + (size_t)kbi * 64 * DHEAD;
#pragma unroll
            for (int c = 0; c < 2; c++) {
                int chk = tid + c * 256;
                int krow = chk >> 3, kc = chk & 7;
                *(uint4*)&Ks[krow * 72 + kc * 8] = *(const uint4*)&src[chk * 8];
            }
            const ushort_t* vsrc = vh + (size_t)kbi * 64 * DHEAD;
#pragma unroll
            for (int c = 0; c < 2; c++) {
                int dh0 = wave * 16 + c * 8;
                uint4 d4 = *(const uint4*)&vsrc[lane * DHEAD + dh0];
                const ushort_t* e = (const ushort_t*)&d4;
#pragma unroll
                for (int j = 0; j < 8; j++) Vs[(dh0 + j) * 72 + lane] = e[j];
            }
        }
        __syncthreads();
        floatx4 sacc[4];
#pragma unroll
        for (int jt = 0; jt < 4; jt++) {
            short8 kf0 = *(const short8*)&Ks[(jt * 16 + l16) * 72 + quad * 8];
            short8 kf1 = *(const short8*)&Ks[(jt * 16 + l16) * 72 + 32 + quad * 8];
            floatx4 z = (floatx4){0.f, 0.f, 0.f, 0.f};
            z = __builtin_amdgcn_mfma_f32_16x16x32_bf16(qf0, kf0, z, 0, 0, 0);
            z = __builtin_amdgcn_mfma_f32_16x16x32_bf16(qf1, kf1, z, 0, 0, 0);
            sacc[jt] = z;
        }
#pragma unroll
        for (int r = 0; r < 4; r++) {
            float mx = fmaxf(fmaxf(sacc[0][r], sacc[1][r]), fmaxf(sacc[2][r], sacc[3][r]));
#pragma unroll
            for (int o = 1; o < 16; o <<= 1) mx = fmaxf(mx, __shfl_xor(mx, o));
            float mnew = fmaxf(mrun[r], mx);
            float al = __expf(mrun[r] - mnew);
            float pv[4], ps = 0.f;
#pragma unroll
            for (int jt = 0; jt < 4; jt++) { pv[jt] = __expf(sacc[jt][r] - mnew); ps += pv[jt]; }
#pragma unroll
            for (int o = 1; o < 16; o <<= 1) ps += __shfl_xor(ps, o);
            lrun[r] = lrun[r] * al + ps;
            mrun[r] = mnew;
#pragma unroll
            for (int jt = 0; jt < 4; jt++) {
                oacc[jt][r] *= al;
                Ps[wave][(quad * 4 + r) * 72 + jt * 16 + l16] = f2bf(pv[jt]);
            }
        }
        short8 pa0 = *(const short8*)&Ps[wave][l16 * 72 + quad * 8];
        short8 pa1 = *(const short8*)&Ps[wave][l16 * 72 + 32 + quad * 8];
#pragma unroll
        for (int jt = 0; jt < 4; jt++) {
            short8 vf0 = *(const short8*)&Vs[(jt * 16 + l16) * 72 + quad * 8];
            short8 vf1 = *(const short8*)&Vs[(jt * 16 + l16) * 72 + 32 + quad * 8];
            oacc[jt] = __builtin_amdgcn_mfma_f32_16x16x32_bf16(pa0, vf0, oacc[jt], 0, 0, 0);
            oacc[jt] = __builtin_amdgcn_mfma_f32_16x16x32_bf16(pa1, vf1, oacc[jt], 0, 0, 0);
        }
    }
    if (mid) {
#pragma unroll
        for (int jt = 0; jt < 4; jt++)
#pragma unroll
            for (int r = 0; r < 4; r++) {
                int row = qblk * 64 + wave * 16 + quad * 4 + r;
                int col = h * DHEAD + jt * 16 + l16;
                out[(size_t)row * DMODEL + col] = f2bf(oacc[jt][r] / lrun[r]);
            }
    } else {
        float* op = opart + ((size_t)(eidx * 8 + chunk)) * 64 * 64;
        float* ml = mlpart + ((size_t)(eidx * 8 + chunk)) * 64 * 2;
#pragma unroll
        for (int jt = 0; jt < 4; jt++)
#pragma unroll
            for (int r = 0; r < 4; r++) {
                int row = wave * 16 + quad * 4 + r;
                op[(size_t)row * 64 + jt * 16 + l16] = oacc[jt][r];
            }
        if (l16 == 0) {
#pragma unroll
            for (int r = 0; r < 4; r++) {
                int row = wave * 16 + quad * 4 + r;
                ml[row * 2 + 0] = mrun[r];
                ml[row * 2 + 1] = lrun[r];
            }
        }
    }
}

// ---------- merge edge split-K partials ----------
__global__ void attn_combine(const float* __restrict__ opart, const float* __restrict__ mlpart,
                             ushort_t* __restrict__ out) {
    int e = blockIdx.x;                  // 0..23
    int side = e / NHEAD, h = e % NHEAD;
    int qblk = side ? (NBLK - 1) : 0;
    __shared__ float mls[8][64][2];
    int tid = threadIdx.x;
    for (int i = tid; i < 8 * 64 * 2; i += 256)
        ((float*)mls)[i] = mlpart[(size_t)e * 8 * 64 * 2 + i];
    __syncthreads();
    int col = tid & 63, r0 = (tid >> 6) * 16;
    const float* ope = opart + (size_t)e * 8 * 64 * 64;
    for (int row = r0; row < r0 + 16; ++row) {
        float M = -1e30f;
#pragma unroll
        for (int p = 0; p < 8; p++) M = fmaxf(M, mls[p][row][0]);
        float L = 0.f, O = 0.f;
#pragma unroll
        for (int p = 0; p < 8; p++) {
            float al = __expf(mls[p][row][0] - M);
            L += mls[p][row][1] * al;
            O += ope[((size_t)p * 64 + row) * 64 + col] * al;
        }
        out[(size_t)(qblk * 64 + row) * DMODEL + h * DHEAD + col] = f2bf(O / L);
    }
}

// ---------- classifier ----------
__global__ void classifier_kernel(const float* __restrict__ hf, const float* __restrict__ Wc,
                                  const float* __restrict__ bc, float* __restrict__ out) {
    int t = threadIdx.x;
    int c = t & 7, seg = t >> 3;
    const float* hr = hf + (size_t)(S_LEN - 1) * DMODEL;
    float p = 0.f;
    for (int i = 0; i < 24; i++) { int d = seg * 24 + i; p += hr[d] * Wc[d * 8 + c]; }
    __shared__ float red[256];
    red[t] = p;
    __syncthreads();
    for (int o = 128; o >= 8; o >>= 1) { if (t < o) red[t] += red[t + o]; __syncthreads(); }
    if (t < 8) out[t] = red[t] + bc[t];
}

// ---------- launch ----------
extern "C" void kernel_launch(void* const* d_in, const int* in_sizes, int n_in,
                              void* d_out, int out_size, void* d_ws, size_t ws_size,
                              hipStream_t stream) {
    (void)in_sizes; (void)n_in; (void)out_size; (void)ws_size;
    const int* input_ids = (const int*)d_in[0];
    const int* rand_attn = (const int*)d_in[1];
    const float* word_emb = (const float*)d_in[2];
    const float* pos_emb = (const float*)d_in[3];
    const float* emb_ln_w = (const float*)d_in[4];
    const float* emb_ln_b = (const float*)d_in[5];
    const float* Wq = (const float*)d_in[6];
    const float* bq = (const float*)d_in[7];
    const float* Wk = (const float*)d_in[8];
    const float* bk = (const float*)d_in[9];
    const float* Wv = (const float*)d_in[10];
    const float* bv = (const float*)d_in[11];
    const float* Wo = (const float*)d_in[12];
    const float* bo = (const float*)d_in[13];
    const float* ln1_w = (const float*)d_in[14];
    const float* ln1_b = (const float*)d_in[15];
    const float* W1 = (const float*)d_in[16];
    const float* b1 = (const float*)d_in[17];
    const float* W2 = (const float*)d_in[18];
    const float* b2 = (const float*)d_in[19];
    const float* ln2_w = (const float*)d_in[20];
    const float* ln2_b = (const float*)d_in[21];
    const float* Wc = (const float*)d_in[22];
    const float* bc = (const float*)d_in[23];
    float* outp = (float*)d_out;

    char* ws = (char*)d_ws;
    size_t off = 0;
    auto alloc = [&](size_t bytes) -> void* {
        void* p = ws + off;
        off += (bytes + 255) & ~(size_t)255;
        return p;
    };
    float* hf = (float*)alloc((size_t)S_LEN * DMODEL * 4);
    ushort_t* hb = (ushort_t*)alloc((size_t)S_LEN * DMODEL * 2);
    float* res = (float*)alloc((size_t)S_LEN * DMODEL * 4);
    ushort_t* WqkvT = (ushort_t*)alloc((size_t)3 * DMODEL * DMODEL * 2);
    ushort_t* WoT = (ushort_t*)alloc((size_t)DMODEL * DMODEL * 2);
    ushort_t* W1T = (ushort_t*)alloc((size_t)FF * DMODEL * 2);
    ushort_t* W2T = (ushort_t*)alloc((size_t)DMODEL * FF * 2);
    ushort_t* qbuf = (ushort_t*)alloc((size_t)NHEAD * S_LEN * DHEAD * 2);
    ushort_t* kbuf = (ushort_t*)alloc((size_t)NHEAD * S_LEN * DHEAD * 2);
    ushort_t* vbuf = (ushort_t*)alloc((size_t)NHEAD * S_LEN * DHEAD * 2);
    ushort_t* attnb = (ushort_t*)alloc((size_t)S_LEN * DMODEL * 2);
    ushort_t* gbuf = (ushort_t*)alloc((size_t)S_LEN * FF * 2);
    float* opart = (float*)alloc((size_t)24 * 8 * 64 * 64 * 4);
    float* mlpart = (float*)alloc((size_t)24 * 8 * 64 * 2 * 4);

    dim3 blk256(256);
    dim3 tb(32, 8);

    embed_ln_kernel<<<S_LEN, blk256, 0, stream>>>(input_ids, word_emb, pos_emb,
                                                  emb_ln_w, emb_ln_b, hf, hb);

    for (int l = 0; l < NLAYER; ++l) {
        const float* Wq_l = Wq + (size_t)l * DMODEL * DMODEL;
        const float* Wk_l = Wk + (size_t)l * DMODEL * DMODEL;
        const float* Wv_l = Wv + (size_t)l * DMODEL * DMODEL;
        const float* Wo_l = Wo + (size_t)l * DMODEL * DMODEL;
        const float* W1_l = W1 + (size_t)l * DMODEL * FF;
        const float* W2_l = W2 + (size_t)l * FF * DMODEL;
        const float* bq_l = bq + (size_t)l * DMODEL;
        const float* bk_l = bk + (size_t)l * DMODEL;
        const float* bv_l = bv + (size_t)l * DMODEL;
        const float* bo_l = bo + (size_t)l * DMODEL;
        const float* b1_l = b1 + (size_t)l * FF;
        const float* b2_l = b2 + (size_t)l * DMODEL;
        const float* ln1w_l = ln1_w + (size_t)l * DMODEL;
        const float* ln1b_l = ln1_b + (size_t)l * DMODEL;
        const float* ln2w_l = ln2_w + (size_t)l * DMODEL;
        const float* ln2b_l = ln2_b + (size_t)l * DMODEL;
        const int* rand_l = rand_attn + (size_t)l * NHEAD * NBLK * 3;

        transpose_cvt<<<dim3(DMODEL / 32, DMODEL / 32), tb, 0, stream>>>(Wq_l, WqkvT, DMODEL, DMODEL);
        transpose_cvt<<<dim3(DMODEL / 32, DMODEL / 32), tb, 0, stream>>>(Wk_l, WqkvT + (size_t)DMODEL * DMODEL, DMODEL, DMODEL);
        transpose_cvt<<<dim3(DMODEL / 32, DMODEL / 32), tb, 0, stream>>>(Wv_l, WqkvT + (size_t)2 * DMODEL * DMODEL, DMODEL, DMODEL);
        transpose_cvt<<<dim3(DMODEL / 32, DMODEL / 32), tb, 0, stream>>>(Wo_l, WoT, DMODEL, DMODEL);
        transpose_cvt<<<dim3(FF / 32, DMODEL / 32), tb, 0, stream>>>(W1_l, W1T, DMODEL, FF);
        transpose_cvt<<<dim3(DMODEL / 32, FF / 32), tb, 0, stream>>>(W2_l, W2T, FF, DMODEL);

        gemm_bf16<0><<<dim3(3 * DMODEL / 128, S_LEN / 128), blk256, 0, stream>>>(
            hb, WqkvT, S_LEN, 3 * DMODEL, DMODEL,
            nullptr, nullptr, nullptr, nullptr, qbuf, kbuf, vbuf, bq_l, bk_l, bv_l);

        attn_kernel<<<NMID + NEDGE_WG, blk256, 0, stream>>>(qbuf, kbuf, vbuf, rand_l,
                                                            attnb, opart, mlpart);
        attn_combine<<<24, blk256, 0, stream>>>(opart, mlpart, attnb);

        gemm_bf16<1><<<dim3(DMODEL / 128, S_LEN / 128), blk256, 0, stream>>>(
            attnb, WoT, S_LEN, DMODEL, DMODEL,
            bo_l, hf, res, nullptr, nullptr, nullptr, nullptr, nullptr, nullptr, nullptr);

        ln_kernel<<<S_LEN, blk256, 0, stream>>>(res, ln1w_l, ln1b_l, hf, hb);

        gemm_bf16<2><<<dim3(FF / 128, S_LEN / 128), blk256, 0, stream>>>(
            hb, W1T, S_LEN, FF, DMODEL,
            b1_l, nullptr, nullptr, gbuf, nullptr, nullptr, nullptr, nullptr, nullptr, nullptr);

        gemm_bf16<1><<<dim3(DMODEL / 128, S_LEN / 128), blk256, 0, stream>>>(
            gbuf, W2T, S_LEN, DMODEL, FF,
            b2_l, hf, res, nullptr, nullptr, nullptr, nullptr, nullptr, nullptr, nullptr);

        ln_kernel<<<S_LEN, blk256, 0, stream>>>(res, ln2w_l, ln2b_l, hf, hb);
    }

    classifier_kernel<<<1, blk256, 0, stream>>>(hf, Wc, bc, outp);
}

// Round 3
// 680.409 us; speedup vs baseline: 1.2930x; 1.0836x over previous
//
#include <hip/hip_runtime.h>
#include <stdint.h>

#define S_LEN 4096
#define DMODEL 768
#define NHEAD 12
#define DHEAD 64
#define NBLK 64
#define FF 3072
#define NLAYER 2
#define NMID (NHEAD * (NBLK - 2))   // 744 mid workgroups
#define NEDGE_WG (NHEAD * 2 * 8)    // 192 edge partial workgroups

typedef __attribute__((ext_vector_type(8))) short short8;
typedef __attribute__((ext_vector_type(4))) float floatx4;
typedef unsigned short ushort_t;

// ---------- helpers ----------
__device__ __forceinline__ unsigned short f2bf(float f) {
    union { float f; unsigned u; } v; v.f = f;
    unsigned r = v.u + 0x7FFFu + ((v.u >> 16) & 1u);  // RNE
    return (unsigned short)(r >> 16);
}

__device__ __forceinline__ float fast_gelu(float v) {
    float u = 0.7978845608f * (v + 0.044715f * v * v * v);
    // tanh(u) = 1 - 2/(exp(2u)+1); saturates correctly for |u| large
    float e = __expf(2.0f * u);
    float th = 1.0f - 2.0f / (e + 1.0f);
    return 0.5f * v * (1.0f + th);
}

__device__ __forceinline__ void load_lds16(const void* g, void* l) {
    __builtin_amdgcn_global_load_lds((const __attribute__((address_space(1))) void*)g,
                                     (__attribute__((address_space(3))) void*)l, 16, 0, 0);
}

// ---------- embedding + LN ----------
__global__ void embed_ln_kernel(const int* __restrict__ ids, const float* __restrict__ wemb,
                                const float* __restrict__ pemb, const float* __restrict__ w,
                                const float* __restrict__ b, float* __restrict__ hf,
                                ushort_t* __restrict__ hb) {
    int s = blockIdx.x, t = threadIdx.x;
    const float* we = wemb + (size_t)ids[s] * DMODEL;
    const float* pe = pemb + (size_t)s * DMODEL;
    float x0 = we[t] + pe[t];
    float x1 = we[t + 256] + pe[t + 256];
    float x2 = we[t + 512] + pe[t + 512];
    float sum = x0 + x1 + x2;
    float sum2 = x0 * x0 + x1 * x1 + x2 * x2;
    __shared__ float sred[8];
    for (int o = 32; o >= 1; o >>= 1) { sum += __shfl_down(sum, o); sum2 += __shfl_down(sum2, o); }
    if ((t & 63) == 0) { sred[t >> 6] = sum; sred[4 + (t >> 6)] = sum2; }
    __syncthreads();
    float ts = sred[0] + sred[1] + sred[2] + sred[3];
    float ts2 = sred[4] + sred[5] + sred[6] + sred[7];
    float mu = ts * (1.0f / DMODEL);
    float rs = rsqrtf(ts2 * (1.0f / DMODEL) - mu * mu + 1e-12f);
    size_t base = (size_t)s * DMODEL;
    float y0 = (x0 - mu) * rs * w[t] + b[t];
    float y1 = (x1 - mu) * rs * w[t + 256] + b[t + 256];
    float y2 = (x2 - mu) * rs * w[t + 512] + b[t + 512];
    hf[base + t] = y0; hf[base + t + 256] = y1; hf[base + t + 512] = y2;
    hb[base + t] = f2bf(y0); hb[base + t + 256] = f2bf(y1); hb[base + t + 512] = f2bf(y2);
}

// ---------- LN ----------
__global__ void ln_kernel(const float* __restrict__ in, const float* __restrict__ w,
                          const float* __restrict__ b, float* __restrict__ hf,
                          ushort_t* __restrict__ hb) {
    int s = blockIdx.x, t = threadIdx.x;
    const float* row = in + (size_t)s * DMODEL;
    float x0 = row[t], x1 = row[t + 256], x2 = row[t + 512];
    float sum = x0 + x1 + x2;
    float sum2 = x0 * x0 + x1 * x1 + x2 * x2;
    __shared__ float sred[8];
    for (int o = 32; o >= 1; o >>= 1) { sum += __shfl_down(sum, o); sum2 += __shfl_down(sum2, o); }
    if ((t & 63) == 0) { sred[t >> 6] = sum; sred[4 + (t >> 6)] = sum2; }
    __syncthreads();
    float ts = sred[0] + sred[1] + sred[2] + sred[3];
    float ts2 = sred[4] + sred[5] + sred[6] + sred[7];
    float mu = ts * (1.0f / DMODEL);
    float rs = rsqrtf(ts2 * (1.0f / DMODEL) - mu * mu + 1e-12f);
    size_t base = (size_t)s * DMODEL;
    float y0 = (x0 - mu) * rs * w[t] + b[t];
    float y1 = (x1 - mu) * rs * w[t + 256] + b[t + 256];
    float y2 = (x2 - mu) * rs * w[t + 512] + b[t + 512];
    hf[base + t] = y0; hf[base + t + 256] = y1; hf[base + t + 512] = y2;
    hb[base + t] = f2bf(y0); hb[base + t + 256] = f2bf(y1); hb[base + t + 512] = f2bf(y2);
}

// ---------- batched fp32 (K x N) -> bf16 transposed (N x K), all 6 weights ----------
__global__ void transpose_all(const float* __restrict__ Wq, const float* __restrict__ Wk,
                              const float* __restrict__ Wv, const float* __restrict__ Wo,
                              const float* __restrict__ W1, const float* __restrict__ W2,
                              ushort_t* __restrict__ WqkvT, ushort_t* __restrict__ WoT,
                              ushort_t* __restrict__ W1T, ushort_t* __restrict__ W2T) {
    __shared__ float tile[32][33];
    int b = blockIdx.x;
    const float* src; ushort_t* dst; int K, N, bx;
    if (b < 2304) {                    // Wq/Wk/Wv/Wo: 4 x (24x24)
        int m = b / 576, r = b % 576;
        src = (m == 0) ? Wq : (m == 1) ? Wk : (m == 2) ? Wv : Wo;
        dst = (m < 3) ? (WqkvT + (size_t)m * DMODEL * DMODEL) : WoT;
        K = DMODEL; N = DMODEL; bx = r;
    } else if (b < 4608) {             // W1: 768 x 3072 -> grid 96 x 24
        src = W1; dst = W1T; K = DMODEL; N = FF; bx = b - 2304;
    } else {                           // W2: 3072 x 768 -> grid 24 x 96
        src = W2; dst = W2T; K = FF; N = DMODEL; bx = b - 4608;
    }
    int gx = N / 32;
    int n0 = (bx % gx) * 32, k0 = (bx / gx) * 32;
    int tx = threadIdx.x, ty = threadIdx.y;  // 32 x 8
    for (int i = 0; i < 32; i += 8)
        tile[ty + i][tx] = src[(size_t)(k0 + ty + i) * N + n0 + tx];
    __syncthreads();
    for (int i = 0; i < 32; i += 8)
        dst[(size_t)(n0 + ty + i) * K + k0 + tx] = f2bf(tile[tx][ty + i]);
}

// ---------- bf16 MFMA GEMM, BK=64, fused epilogues ----------
// MODE 0: QKV scatter; MODE 1: fp32 acc+bias+resid; MODE 2: bf16 gelu(acc+bias)
template <int MODE>
__global__ __launch_bounds__(256, 2) void gemm_bf16(
    const ushort_t* __restrict__ A, const ushort_t* __restrict__ BT,
    int M, int N, int K,
    const float* __restrict__ bias, const float* __restrict__ resid,
    float* __restrict__ outf, ushort_t* __restrict__ outb,
    ushort_t* __restrict__ qout, ushort_t* __restrict__ kout, ushort_t* __restrict__ vout,
    const float* __restrict__ bq, const float* __restrict__ bk, const float* __restrict__ bv) {
    __shared__ __align__(16) ushort_t Asm[128 * 64];
    __shared__ __align__(16) ushort_t Bsm[128 * 64];
    int tid = threadIdx.x;
    int lane = tid & 63, wave = tid >> 6;
    int quad = lane >> 4, l16 = lane & 15;
    int wm = wave >> 1, wn = wave & 1;
    long arow0 = (long)blockIdx.y * 128;
    long bcol0 = (long)blockIdx.x * 128;
    // staging: lane covers (r8 = lane>>3) row-in-8, chunk c = lane&7 (16B each).
    // LDS[row][slot] = data[row][slot ^ (row&7)] -> write-side source chunk = c ^ (r8&7).
    int r8 = lane >> 3;
    int gchunk = (lane & 7) ^ (r8 & 7);
    const ushort_t* agp0 = A + (arow0 + r8) * (long)K + gchunk * 8;
    const ushort_t* bgp0 = BT + (bcol0 + r8) * (long)K + gchunk * 8;
    floatx4 acc[4][4];
#pragma unroll
    for (int i = 0; i < 4; i++)
#pragma unroll
        for (int j = 0; j < 4; j++) acc[i][j] = (floatx4){0.f, 0.f, 0.f, 0.f};

    for (int k0 = 0; k0 < K; k0 += 64) {
        __syncthreads();
#pragma unroll
        for (int t2 = 0; t2 < 4; t2++) {
            int seg = wave * 4 + t2;  // 8 rows per segment
            load_lds16(agp0 + (long)seg * 8 * K + k0, Asm + seg * 512);
            load_lds16(bgp0 + (long)seg * 8 * K + k0, Bsm + seg * 512);
        }
        __syncthreads();
#pragma unroll
        for (int ks = 0; ks < 2; ks++) {
            short8 af[4], bfv[4];
#pragma unroll
            for (int i = 0; i < 4; i++)
                af[i] = *(const short8*)&Asm[(wm * 64 + i * 16 + l16) * 64 +
                                             (((ks * 4 + quad) ^ (l16 & 7)) * 8)];
#pragma unroll
            for (int j = 0; j < 4; j++)
                bfv[j] = *(const short8*)&Bsm[(wn * 64 + j * 16 + l16) * 64 +
                                              (((ks * 4 + quad) ^ (l16 & 7)) * 8)];
#pragma unroll
            for (int i = 0; i < 4; i++)
#pragma unroll
                for (int j = 0; j < 4; j++)
                    acc[i][j] = __builtin_amdgcn_mfma_f32_16x16x32_bf16(af[i], bfv[j], acc[i][j], 0, 0, 0);
        }
    }

#pragma unroll
    for (int i = 0; i < 4; i++) {
        long row = arow0 + wm * 64 + i * 16 + quad * 4;
#pragma unroll
        for (int j = 0; j < 4; j++) {
            long col = bcol0 + wn * 64 + j * 16 + l16;
#pragma unroll
            for (int r = 0; r < 4; r++) {
                float v = acc[i][j][r];
                long rw = row + r;
                if (MODE == 0) {
                    int n = (int)col;
                    if (n < DMODEL) {
                        v = (v + bq[n]) * 0.125f;
                        int hh = n >> 6, dh = n & 63;
                        qout[((long)hh * S_LEN + rw) * DHEAD + dh] = f2bf(v);
                    } else if (n < 2 * DMODEL) {
                        int n2 = n - DMODEL; v += bk[n2];
                        int hh = n2 >> 6, dh = n2 & 63;
                        kout[((long)hh * S_LEN + rw) * DHEAD + dh] = f2bf(v);
                    } else {
                        int n2 = n - 2 * DMODEL; v += bv[n2];
                        int hh = n2 >> 6, dh = n2 & 63;
                        vout[((long)hh * S_LEN + rw) * DHEAD + dh] = f2bf(v);
                    }
                } else if (MODE == 1) {
                    v += bias[col] + resid[rw * (long)N + col];
                    outf[rw * (long)N + col] = v;
                } else {
                    v += bias[col];
                    outb[rw * (long)N + col] = f2bf(fast_gelu(v));
                }
            }
        }
    }
}

// ---------- BigBird attention, load-balanced (mid direct, edges split-K) ----------
__global__ __launch_bounds__(256, 2) void attn_kernel(
    const ushort_t* __restrict__ qb, const ushort_t* __restrict__ kb,
    const ushort_t* __restrict__ vb, const int* __restrict__ randl,
    ushort_t* __restrict__ out, float* __restrict__ opart, float* __restrict__ mlpart) {
    __shared__ __align__(16) ushort_t Ks[64 * 72];
    __shared__ __align__(16) ushort_t Vs[64 * 72];
    __shared__ __align__(16) ushort_t Ps[4][16 * 72];
    __shared__ int kls[8];
    int tid = threadIdx.x, lane = tid & 63, wave = tid >> 6, quad = lane >> 4, l16 = lane & 15;
    int g = blockIdx.x;
    int h, qblk, chunk = 0, eidx = 0;
    bool mid;
    if (g < NMID) {
        mid = true;
        h = g / (NBLK - 2);
        qblk = 1 + g % (NBLK - 2);
    } else {
        mid = false;
        int t = g - NMID;
        int side = t / (NHEAD * 8);
        int t2 = t % (NHEAD * 8);
        h = t2 >> 3;
        chunk = t2 & 7;
        qblk = side ? (NBLK - 1) : 0;
        eidx = side * NHEAD + h;
    }
    if (mid && tid < 8) {
        int v;
        if (tid == 0) v = 0;
        else if (tid == 1) v = NBLK - 1;
        else if (tid == 2) v = qblk - 1;
        else if (tid == 3) v = qblk;
        else if (tid == 4) v = qblk + 1;
        else v = randl[(h * NBLK + qblk) * 3 + (tid - 5)];
        kls[tid] = v;
    }
    const ushort_t* qh = qb + (size_t)h * S_LEN * DHEAD;
    const ushort_t* kh = kb + (size_t)h * S_LEN * DHEAD;
    const ushort_t* vh = vb + (size_t)h * S_LEN * DHEAD;
    size_t qoff = ((size_t)(qblk * 64 + wave * 16 + l16)) * DHEAD;
    short8 qf0 = *(const short8*)&qh[qoff + quad * 8];
    short8 qf1 = *(const short8*)&qh[qoff + 32 + quad * 8];
    floatx4 oacc[4];
#pragma unroll
    for (int j = 0; j < 4; j++) oacc[j] = (floatx4){0.f, 0.f, 0.f, 0.f};
    float mrun[4] = {-1e30f, -1e30f, -1e30f, -1e30f};
    float lrun[4] = {0.f, 0.f, 0.f, 0.f};

    for (int it = 0; it < 8; ++it) {
        __syncthreads();
        int kbi = mid ? kls[it] : (chunk * 8 + it);
        {
            const ushort_t* src = kh + (size_t)kbi * 64 * DHEAD;
#pragma unroll
            for (int c = 0; c < 2; c++) {
                int chk = tid + c * 256;
                int krow = chk >> 3, kc = chk & 7;
                *(uint4*)&Ks[krow * 72 + kc * 8] = *(const uint4*)&src[chk * 8];
            }
            const ushort_t* vsrc = vh + (size_t)kbi * 64 * DHEAD;
#pragma unroll
            for (int c = 0; c < 2; c++) {
                int dh0 = wave * 16 + c * 8;
                uint4 d4 = *(const uint4*)&vsrc[lane * DHEAD + dh0];
                const ushort_t* e = (const ushort_t*)&d4;
#pragma unroll
                for (int j = 0; j < 8; j++) Vs[(dh0 + j) * 72 + lane] = e[j];
            }
        }
        __syncthreads();
        floatx4 sacc[4];
#pragma unroll
        for (int jt = 0; jt < 4; jt++) {
            short8 kf0 = *(const short8*)&Ks[(jt * 16 + l16) * 72 + quad * 8];
            short8 kf1 = *(const short8*)&Ks[(jt * 16 + l16) * 72 + 32 + quad * 8];
            floatx4 z = (floatx4){0.f, 0.f, 0.f, 0.f};
            z = __builtin_amdgcn_mfma_f32_16x16x32_bf16(qf0, kf0, z, 0, 0, 0);
            z = __builtin_amdgcn_mfma_f32_16x16x32_bf16(qf1, kf1, z, 0, 0, 0);
            sacc[jt] = z;
        }
#pragma unroll
        for (int r = 0; r < 4; r++) {
            float mx = fmaxf(fmaxf(sacc[0][r], sacc[1][r]), fmaxf(sacc[2][r], sacc[3][r]));
#pragma unroll
            for (int o = 1; o < 16; o <<= 1) mx = fmaxf(mx, __shfl_xor(mx, o));
            float mnew = fmaxf(mrun[r], mx);
            float al = __expf(mrun[r] - mnew);
            float pv[4], ps = 0.f;
#pragma unroll
            for (int jt = 0; jt < 4; jt++) { pv[jt] = __expf(sacc[jt][r] - mnew); ps += pv[jt]; }
#pragma unroll
            for (int o = 1; o < 16; o <<= 1) ps += __shfl_xor(ps, o);
            lrun[r] = lrun[r] * al + ps;
            mrun[r] = mnew;
#pragma unroll
            for (int jt = 0; jt < 4; jt++) {
                oacc[jt][r] *= al;
                Ps[wave][(quad * 4 + r) * 72 + jt * 16 + l16] = f2bf(pv[jt]);
            }
        }
        short8 pa0 = *(const short8*)&Ps[wave][l16 * 72 + quad * 8];
        short8 pa1 = *(const short8*)&Ps[wave][l16 * 72 + 32 + quad * 8];
#pragma unroll
        for (int jt = 0; jt < 4; jt++) {
            short8 vf0 = *(const short8*)&Vs[(jt * 16 + l16) * 72 + quad * 8];
            short8 vf1 = *(const short8*)&Vs[(jt * 16 + l16) * 72 + 32 + quad * 8];
            oacc[jt] = __builtin_amdgcn_mfma_f32_16x16x32_bf16(pa0, vf0, oacc[jt], 0, 0, 0);
            oacc[jt] = __builtin_amdgcn_mfma_f32_16x16x32_bf16(pa1, vf1, oacc[jt], 0, 0, 0);
        }
    }
    if (mid) {
#pragma unroll
        for (int jt = 0; jt < 4; jt++)
#pragma unroll
            for (int r = 0; r < 4; r++) {
                int row = qblk * 64 + wave * 16 + quad * 4 + r;
                int col = h * DHEAD + jt * 16 + l16;
                out[(size_t)row * DMODEL + col] = f2bf(oacc[jt][r] / lrun[r]);
            }
    } else {
        float* op = opart + ((size_t)(eidx * 8 + chunk)) * 64 * 64;
        float* ml = mlpart + ((size_t)(eidx * 8 + chunk)) * 64 * 2;
#pragma unroll
        for (int jt = 0; jt < 4; jt++)
#pragma unroll
            for (int r = 0; r < 4; r++) {
                int row = wave * 16 + quad * 4 + r;
                op[(size_t)row * 64 + jt * 16 + l16] = oacc[jt][r];
            }
        if (l16 == 0) {
#pragma unroll
            for (int r = 0; r < 4; r++) {
                int row = wave * 16 + quad * 4 + r;
                ml[row * 2 + 0] = mrun[r];
                ml[row * 2 + 1] = lrun[r];
            }
        }
    }
}

// ---------- merge edge split-K partials ----------
__global__ void attn_combine(const float* __restrict__ opart, const float* __restrict__ mlpart,
                             ushort_t* __restrict__ out) {
    int e = blockIdx.x;                  // 0..23
    int side = e / NHEAD, h = e % NHEAD;
    int qblk = side ? (NBLK - 1) : 0;
    __shared__ float mls[8][64][2];
    int tid = threadIdx.x;
    for (int i = tid; i < 8 * 64 * 2; i += 256)
        ((float*)mls)[i] = mlpart[(size_t)e * 8 * 64 * 2 + i];
    __syncthreads();
    int col = tid & 63, r0 = (tid >> 6) * 16;
    const float* ope = opart + (size_t)e * 8 * 64 * 64;
    for (int row = r0; row < r0 + 16; ++row) {
        float M = -1e30f;
#pragma unroll
        for (int p = 0; p < 8; p++) M = fmaxf(M, mls[p][row][0]);
        float L = 0.f, O = 0.f;
#pragma unroll
        for (int p = 0; p < 8; p++) {
            float al = __expf(mls[p][row][0] - M);
            L += mls[p][row][1] * al;
            O += ope[((size_t)p * 64 + row) * 64 + col] * al;
        }
        out[(size_t)(qblk * 64 + row) * DMODEL + h * DHEAD + col] = f2bf(O / L);
    }
}

// ---------- classifier ----------
__global__ void classifier_kernel(const float* __restrict__ hf, const float* __restrict__ Wc,
                                  const float* __restrict__ bc, float* __restrict__ out) {
    int t = threadIdx.x;
    int c = t & 7, seg = t >> 3;
    const float* hr = hf + (size_t)(S_LEN - 1) * DMODEL;
    float p = 0.f;
    for (int i = 0; i < 24; i++) { int d = seg * 24 + i; p += hr[d] * Wc[d * 8 + c]; }
    __shared__ float red[256];
    red[t] = p;
    __syncthreads();
    for (int o = 128; o >= 8; o >>= 1) { if (t < o) red[t] += red[t + o]; __syncthreads(); }
    if (t < 8) out[t] = red[t] + bc[t];
}

// ---------- launch ----------
extern "C" void kernel_launch(void* const* d_in, const int* in_sizes, int n_in,
                              void* d_out, int out_size, void* d_ws, size_t ws_size,
                              hipStream_t stream) {
    (void)in_sizes; (void)n_in; (void)out_size; (void)ws_size;
    const int* input_ids = (const int*)d_in[0];
    const int* rand_attn = (const int*)d_in[1];
    const float* word_emb = (const float*)d_in[2];
    const float* pos_emb = (const float*)d_in[3];
    const float* emb_ln_w = (const float*)d_in[4];
    const float* emb_ln_b = (const float*)d_in[5];
    const float* Wq = (const float*)d_in[6];
    const float* bq = (const float*)d_in[7];
    const float* Wk = (const float*)d_in[8];
    const float* bk = (const float*)d_in[9];
    const float* Wv = (const float*)d_in[10];
    const float* bv = (const float*)d_in[11];
    const float* Wo = (const float*)d_in[12];
    const float* bo = (const float*)d_in[13];
    const float* ln1_w = (const float*)d_in[14];
    const float* ln1_b = (const float*)d_in[15];
    const float* W1 = (const float*)d_in[16];
    const float* b1 = (const float*)d_in[17];
    const float* W2 = (const float*)d_in[18];
    const float* b2 = (const float*)d_in[19];
    const float* ln2_w = (const float*)d_in[20];
    const float* ln2_b = (const float*)d_in[21];
    const float* Wc = (const float*)d_in[22];
    const float* bc = (const float*)d_in[23];
    float* outp = (float*)d_out;

    char* ws = (char*)d_ws;
    size_t off = 0;
    auto alloc = [&](size_t bytes) -> void* {
        void* p = ws + off;
        off += (bytes + 255) & ~(size_t)255;
        return p;
    };
    float* hf = (float*)alloc((size_t)S_LEN * DMODEL * 4);
    ushort_t* hb = (ushort_t*)alloc((size_t)S_LEN * DMODEL * 2);
    float* res = (float*)alloc((size_t)S_LEN * DMODEL * 4);
    ushort_t* WqkvT = (ushort_t*)alloc((size_t)3 * DMODEL * DMODEL * 2);
    ushort_t* WoT = (ushort_t*)alloc((size_t)DMODEL * DMODEL * 2);
    ushort_t* W1T = (ushort_t*)alloc((size_t)FF * DMODEL * 2);
    ushort_t* W2T = (ushort_t*)alloc((size_t)DMODEL * FF * 2);
    ushort_t* qbuf = (ushort_t*)alloc((size_t)NHEAD * S_LEN * DHEAD * 2);
    ushort_t* kbuf = (ushort_t*)alloc((size_t)NHEAD * S_LEN * DHEAD * 2);
    ushort_t* vbuf = (ushort_t*)alloc((size_t)NHEAD * S_LEN * DHEAD * 2);
    ushort_t* attnb = (ushort_t*)alloc((size_t)S_LEN * DMODEL * 2);
    ushort_t* gbuf = (ushort_t*)alloc((size_t)S_LEN * FF * 2);
    float* opart = (float*)alloc((size_t)24 * 8 * 64 * 64 * 4);
    float* mlpart = (float*)alloc((size_t)24 * 8 * 64 * 2 * 4);

    dim3 blk256(256);
    dim3 tb(32, 8);

    embed_ln_kernel<<<S_LEN, blk256, 0, stream>>>(input_ids, word_emb, pos_emb,
                                                  emb_ln_w, emb_ln_b, hf, hb);

    for (int l = 0; l < NLAYER; ++l) {
        const float* Wq_l = Wq + (size_t)l * DMODEL * DMODEL;
        const float* Wk_l = Wk + (size_t)l * DMODEL * DMODEL;
        const float* Wv_l = Wv + (size_t)l * DMODEL * DMODEL;
        const float* Wo_l = Wo + (size_t)l * DMODEL * DMODEL;
        const float* W1_l = W1 + (size_t)l * DMODEL * FF;
        const float* W2_l = W2 + (size_t)l * FF * DMODEL;
        const float* bq_l = bq + (size_t)l * DMODEL;
        const float* bk_l = bk + (size_t)l * DMODEL;
        const float* bv_l = bv + (size_t)l * DMODEL;
        const float* bo_l = bo + (size_t)l * DMODEL;
        const float* b1_l = b1 + (size_t)l * FF;
        const float* b2_l = b2 + (size_t)l * DMODEL;
        const float* ln1w_l = ln1_w + (size_t)l * DMODEL;
        const float* ln1b_l = ln1_b + (size_t)l * DMODEL;
        const float* ln2w_l = ln2_w + (size_t)l * DMODEL;
        const float* ln2b_l = ln2_b + (size_t)l * DMODEL;
        const int* rand_l = rand_attn + (size_t)l * NHEAD * NBLK * 3;

        transpose_all<<<6912, tb, 0, stream>>>(Wq_l, Wk_l, Wv_l, Wo_l, W1_l, W2_l,
                                               WqkvT, WoT, W1T, W2T);

        gemm_bf16<0><<<dim3(3 * DMODEL / 128, S_LEN / 128), blk256, 0, stream>>>(
            hb, WqkvT, S_LEN, 3 * DMODEL, DMODEL,
            nullptr, nullptr, nullptr, nullptr, qbuf, kbuf, vbuf, bq_l, bk_l, bv_l);

        attn_kernel<<<NMID + NEDGE_WG, blk256, 0, stream>>>(qbuf, kbuf, vbuf, rand_l,
                                                            attnb, opart, mlpart);
        attn_combine<<<24, blk256, 0, stream>>>(opart, mlpart, attnb);

        gemm_bf16<1><<<dim3(DMODEL / 128, S_LEN / 128), blk256, 0, stream>>>(
            attnb, WoT, S_LEN, DMODEL, DMODEL,
            bo_l, hf, res, nullptr, nullptr, nullptr, nullptr, nullptr, nullptr, nullptr);

        ln_kernel<<<S_LEN, blk256, 0, stream>>>(res, ln1w_l, ln1b_l, hf, hb);

        gemm_bf16<2><<<dim3(FF / 128, S_LEN / 128), blk256, 0, stream>>>(
            hb, W1T, S_LEN, FF, DMODEL,
            b1_l, nullptr, nullptr, gbuf, nullptr, nullptr, nullptr, nullptr, nullptr, nullptr);

        gemm_bf16<1><<<dim3(DMODEL / 128, S_LEN / 128), blk256, 0, stream>>>(
            gbuf, W2T, S_LEN, DMODEL, FF,
            b2_l, hf, res, nullptr, nullptr, nullptr, nullptr, nullptr, nullptr, nullptr);

        ln_kernel<<<S_LEN, blk256, 0, stream>>>(res, ln2w_l, ln2b_l, hf, hb);
    }

    classifier_kernel<<<1, blk256, 0, stream>>>(hf, Wc, bc, outp);
}